// Round 12
// baseline (220.495 us; speedup 1.0000x reference)
//
#include <hip/hip_runtime.h>
#include <hip/hip_bf16.h>

#define B_ 32
#define T_ 512
#define F_ 9
#define H_ 64
#define P_ 84
#define LE_ 510
#define LBL_ 10

struct CombT { int c[P_][3]; };
__host__ __device__ constexpr CombT make_combs() {
    CombT t{}; int n = 0;
    for (int a = 0; a < F_; ++a)
        for (int b = a + 1; b < F_; ++b)
            for (int c = b + 1; c < F_; ++c) { t.c[n][0] = a; t.c[n][1] = b; t.c[n][2] = c; ++n; }
    return t;
}
constexpr CombT COMB_H = make_combs();

// ---------------------------------------------------------------------------
// Kernel A: A[h][f*3+k] = sum_p va_w1[p] * sum_i [comb[p][i]==f] w[p,h,i,k]
//           Abias[h]    = va_b1[h] + sum_p va_w1[p]*conv_b[p,h]
// ---------------------------------------------------------------------------
__global__ __launch_bounds__(256) void precomp_kernel(
    const float* __restrict__ conv_w, const float* __restrict__ conv_b,
    const float* __restrict__ va_w1, const float* __restrict__ va_b1,
    float* __restrict__ A, float* __restrict__ Abias)
{
    __shared__ float sacc[256][28];
    int tid = threadIdx.x;
    int h = tid >> 2, q = tid & 3;            // 64 h  x  4 p-quarters
    for (int j = 0; j < 28; ++j) sacc[tid][j] = 0.f;
    for (int p = q * 21; p < (q + 1) * 21; ++p) {
        float w1 = va_w1[p];
        sacc[tid][27] += w1 * conv_b[p * H_ + h];
        const float* wp = conv_w + p * (H_ * 9) + h * 9;
        for (int i = 0; i < 3; ++i) {
            int f = COMB_H.c[p][i];
            for (int k = 0; k < 3; ++k) sacc[tid][f * 3 + k] += w1 * wp[i * 3 + k];
        }
    }
    __syncthreads();
    if (q == 0) {
        for (int j = 0; j < 27; ++j)
            A[h * 27 + j] = sacc[tid][j] + sacc[tid + 1][j] + sacc[tid + 2][j] + sacc[tid + 3][j];
        Abias[h] = va_b1[h] + sacc[tid][27] + sacc[tid + 1][27] + sacc[tid + 2][27] + sacc[tid + 3][27];
    }
}

// ---------------------------------------------------------------------------
// transpose_kernel: cwT2[p][h][12]: j=0..8 taps (i*3+k), j=9 bias, pad 2.
// ---------------------------------------------------------------------------
__global__ __launch_bounds__(512) void transpose_kernel(
    const float* __restrict__ conv_w, const float* __restrict__ conv_b,
    float* __restrict__ cwT2)
{
    int i = blockIdx.x * 512 + threadIdx.x;      // 85*768 = 65280
    if (i >= 85 * 768) return;
    int p = i / 768, r = i - p * 768;
    int h = r / 12, j = r - h * 12;
    float val = 0.f;
    if (p < P_) {
        if (j < 9) val = conv_w[(p * H_ + h) * 9 + j];
        else if (j == 9) val = conv_b[p * H_ + h];
    }
    cwT2[i] = val;
}

// ---------------------------------------------------------------------------
// attn_kernel: per (ltile, b), 1024 threads (16 waves), lane = l.
// ---------------------------------------------------------------------------
__global__ __launch_bounds__(1024) void attn_kernel(
    const float* __restrict__ x,
    const float* __restrict__ va_w2, const float* __restrict__ va_b2,
    const float* __restrict__ A, const float* __restrict__ Abias,
    float* __restrict__ aw)
{
    __shared__ float xs[66 * 9];
    __shared__ float t1s[64][65];
    __shared__ float t2s[64][85];

    const int b = blockIdx.y;
    const int lt = blockIdx.x;
    const int l0 = lt * 64;
    const int tid = threadIdx.x;
    const int ln = tid & 63;
    const int wv = tid >> 6;            // 0..15

    int maxidx = (T_ - l0) * F_; if (maxidx > 66 * F_) maxidx = 66 * F_;
    for (int i = tid; i < 66 * F_; i += 1024)
        xs[i] = (i < maxidx) ? x[b * (T_ * F_) + l0 * F_ + i] : 0.f;
    __syncthreads();

    float xw[27];
#pragma unroll
    for (int k = 0; k < 3; ++k)
#pragma unroll
        for (int f = 0; f < F_; ++f) xw[k * 9 + f] = xs[(ln + k) * F_ + f];

#pragma unroll
    for (int hh = 0; hh < 4; ++hh) {
        int h = wv * 4 + hh;
        const float* Ah = A + h * 27;
        float s = Abias[h];
#pragma unroll
        for (int f = 0; f < F_; ++f)
#pragma unroll
            for (int k = 0; k < 3; ++k) s = fmaf(xw[k * 9 + f], Ah[f * 3 + k], s);
        t1s[ln][h] = fmaxf(s, 0.f);
    }
    __syncthreads();

    const int cnt = (wv < 4) ? 6 : 5;
    const int p0 = (wv < 4) ? wv * 6 : 24 + (wv - 4) * 5;
    {
        float t2acc[6];
#pragma unroll
        for (int j = 0; j < 6; ++j) t2acc[j] = (j < cnt) ? va_b2[p0 + j] : 0.f;
        for (int h = 0; h < H_; ++h) {
            float tv = t1s[ln][h];
            const float* w2h = va_w2 + h * P_ + p0;
#pragma unroll
            for (int j = 0; j < 6; ++j)
                if (j < cnt) t2acc[j] = fmaf(tv, w2h[j], t2acc[j]);
        }
#pragma unroll
        for (int j = 0; j < 6; ++j)
            if (j < cnt) t2s[ln][p0 + j] = fmaxf(t2acc[j], 0.f);
    }
    __syncthreads();

    float mx = -1e30f;
    for (int p = 0; p < P_; ++p) mx = fmaxf(mx, t2s[ln][p]);
    float sum = 0.f;
    for (int p = 0; p < P_; ++p) sum += __expf(t2s[ln][p] - mx);
    float inv = 1.f / sum;

    const int awbase = (b * 8 + lt) * P_;
#pragma unroll
    for (int j = 0; j < 6; ++j)
        if (j < cnt)
            aw[(awbase + p0 + j) * 64 + ln] = __expf(t2s[ln][p0 + j] - mx) * inv;
}

// ---------------------------------------------------------------------------
// passB_kernel v10: grid (lt 8, b 32, z 8), 256 thr (4 waves), lane = l.
// Each wave owns an h-PAIR (h0 = z*8 + wv*2); all 84 p's template-unrolled
// (static comb indices, xw[27] in VGPRs).  Weights: wave-uniform
// s_load_dwordx4 (SGPRs, no VGPR cost).  ap: per-lane coalesced GLOBAL
// loads (vmcnt-pipelined; aw is L2-resident) -- no aws LDS, so LDS = 2.4 KB
// and 8 blocks/CU = 32 waves/CU hide the SMEM latency (R11 limiter).
// ---------------------------------------------------------------------------
template<int PI>
__device__ __forceinline__ void pb_step(
    const float* __restrict__ wbase, const float* __restrict__ awp,
    const float (&xw)[27], float& acc0, float& acc1)
{
    const int f0 = COMB_H.c[PI][0];     // folds: PI is a template constant
    const int f1 = COMB_H.c[PI][1];
    const int f2 = COMB_H.c[PI][2];
    const float4* wq = reinterpret_cast<const float4*>(wbase + PI * 768);
    const float4 w0 = wq[0], w1 = wq[1], w2 = wq[2];
    const float4 w3 = wq[3], w4 = wq[4], w5 = wq[5];
    const float ap = awp[PI * 64];

    float cv0 = w2.y;                    // bias h0
    cv0 = fmaf(w0.x, xw[0 * 9 + f0], cv0);
    cv0 = fmaf(w0.y, xw[1 * 9 + f0], cv0);
    cv0 = fmaf(w0.z, xw[2 * 9 + f0], cv0);
    cv0 = fmaf(w0.w, xw[0 * 9 + f1], cv0);
    cv0 = fmaf(w1.x, xw[1 * 9 + f1], cv0);
    cv0 = fmaf(w1.y, xw[2 * 9 + f1], cv0);
    cv0 = fmaf(w1.z, xw[0 * 9 + f2], cv0);
    cv0 = fmaf(w1.w, xw[1 * 9 + f2], cv0);
    cv0 = fmaf(w2.x, xw[2 * 9 + f2], cv0);

    float cv1 = w5.y;                    // bias h0+1
    cv1 = fmaf(w3.x, xw[0 * 9 + f0], cv1);
    cv1 = fmaf(w3.y, xw[1 * 9 + f0], cv1);
    cv1 = fmaf(w3.z, xw[2 * 9 + f0], cv1);
    cv1 = fmaf(w3.w, xw[0 * 9 + f1], cv1);
    cv1 = fmaf(w4.x, xw[1 * 9 + f1], cv1);
    cv1 = fmaf(w4.y, xw[2 * 9 + f1], cv1);
    cv1 = fmaf(w4.z, xw[0 * 9 + f2], cv1);
    cv1 = fmaf(w4.w, xw[1 * 9 + f2], cv1);
    cv1 = fmaf(w5.x, xw[2 * 9 + f2], cv1);

    acc0 = fmaf(ap, cv0, acc0);
    acc1 = fmaf(ap, cv1, acc1);
}

template<int PI, int N>
__device__ __forceinline__ void pb_run(
    const float* __restrict__ wbase, const float* __restrict__ awp,
    const float (&xw)[27], float& acc0, float& acc1)
{
    if constexpr (N == 1) {
        pb_step<PI>(wbase, awp, xw, acc0, acc1);
    } else {
        pb_run<PI, N / 2>(wbase, awp, xw, acc0, acc1);
        pb_run<PI + N / 2, N - N / 2>(wbase, awp, xw, acc0, acc1);
    }
}

__global__ __launch_bounds__(256, 8) void passB_kernel(
    const float* __restrict__ x,
    const float* __restrict__ cwT2,
    const float* __restrict__ aw,
    float* __restrict__ v)
{
    __shared__ float xraw[66 * 9];           // 2376 B total LDS

    const int lt = blockIdx.x;
    const int b  = blockIdx.y;
    const int z  = blockIdx.z;               // 0..7
    const int l0 = lt * 64;
    const int tid = threadIdx.x;
    const int ln  = tid & 63;
    const int wvu = __builtin_amdgcn_readfirstlane(tid >> 6);   // 0..3 scalar

    // ---- stage x rows (coalesced) ----
    int maxidx = (T_ - l0) * F_; if (maxidx > 66 * F_) maxidx = 66 * F_;
    for (int i = tid; i < 66 * F_; i += 256)
        xraw[i] = (i < maxidx) ? x[b * (T_ * F_) + l0 * F_ + i] : 0.f;
    __syncthreads();

    // ---- per-lane x window in registers (static indices only) ----
    float xw[27];
#pragma unroll
    for (int k = 0; k < 3; ++k)
#pragma unroll
        for (int f = 0; f < F_; ++f) xw[k * 9 + f] = xraw[(ln + k) * F_ + f];

    const int h0 = z * 8 + wvu * 2;
    const float* wbase = cwT2 + h0 * 12;                        // + p*768
    const float* awp   = aw + (b * 8 + lt) * (P_ * 64) + ln;    // + p*64
    float acc0 = 0.f, acc1 = 0.f;

    pb_run<0, P_>(wbase, awp, xw, acc0, acc1);

    const int l = l0 + ln;
    if (l < LE_) {
        v[(b * H_ + h0 + 0) * LE_ + l] = acc0;
        v[(b * H_ + h0 + 1) * LE_ + l] = acc1;
    }
}

// ---------------------------------------------------------------------------
// ta_kernel v2 (proven R5): one block per b, 512 threads (8 waves).
// v layout [b][h][l]; all loads coalesced; shuffle reductions.
// ---------------------------------------------------------------------------
__global__ __launch_bounds__(512) void ta_kernel(
    const float* __restrict__ v,
    const float* __restrict__ ta_w1, const float* __restrict__ ta_b1,
    const float* __restrict__ ta_w2, const float* __restrict__ ta_b2,
    const float* __restrict__ fc_w, const float* __restrict__ fc_b,
    float* __restrict__ out)
{
    __shared__ float u1s[64];
    __shared__ float attns[512];
    __shared__ float red8[8];
    __shared__ float zs[64];

    const int b = blockIdx.x;
    const int tid = threadIdx.x;
    const int ln = tid & 63;
    const int wv = tid >> 6;             // 0..7
    const float* vb = v + b * (H_ * LE_);

#pragma unroll
    for (int hh = 0; hh < 8; ++hh) {
        const int h = wv * 8 + hh;
        const float* row = vb + h * LE_;
        float s = 0.f;
#pragma unroll
        for (int it = 0; it < 8; ++it) {
            int l = it * 64 + ln;
            if (l < LE_) s = fmaf(row[l], ta_w1[l], s);
        }
#pragma unroll
        for (int off = 32; off > 0; off >>= 1) s += __shfl_xor(s, off);
        if (ln == 0) u1s[h] = fmaxf(s + ta_b1[h], 0.f);
    }
    __syncthreads();

    float val = -1e30f;
    if (tid < LE_) {
        float s0 = ta_b2[tid], s1 = 0.f, s2 = 0.f, s3 = 0.f;
#pragma unroll
        for (int h = 0; h < H_; h += 4) {
            s0 = fmaf(u1s[h + 0], ta_w2[(h + 0) * LE_ + tid], s0);
            s1 = fmaf(u1s[h + 1], ta_w2[(h + 1) * LE_ + tid], s1);
            s2 = fmaf(u1s[h + 2], ta_w2[(h + 2) * LE_ + tid], s2);
            s3 = fmaf(u1s[h + 3], ta_w2[(h + 3) * LE_ + tid], s3);
        }
        val = fmaxf((s0 + s1) + (s2 + s3), 0.f);
    }

    float m = val;
#pragma unroll
    for (int off = 32; off > 0; off >>= 1) m = fmaxf(m, __shfl_xor(m, off));
    if (ln == 0) red8[wv] = m;
    __syncthreads();
    float M = red8[0];
#pragma unroll
    for (int i = 1; i < 8; ++i) M = fmaxf(M, red8[i]);

    float e = (tid < LE_) ? __expf(val - M) : 0.f;
    float s = e;
#pragma unroll
    for (int off = 32; off > 0; off >>= 1) s += __shfl_xor(s, off);
    __syncthreads();
    if (ln == 0) red8[wv] = s;
    __syncthreads();
    float S = red8[0];
#pragma unroll
    for (int i = 1; i < 8; ++i) S += red8[i];
    attns[tid] = e * (1.f / S);
    __syncthreads();

#pragma unroll
    for (int hh = 0; hh < 8; ++hh) {
        const int h = wv * 8 + hh;
        const float* row = vb + h * LE_;
        float t = 0.f;
#pragma unroll
        for (int it = 0; it < 8; ++it) {
            int l = it * 64 + ln;
            if (l < LE_) t = fmaf(row[l], attns[l], t);
        }
#pragma unroll
        for (int off = 32; off > 0; off >>= 1) t += __shfl_xor(t, off);
        if (ln == 0) zs[h] = t;
    }
    __syncthreads();

    if (tid < LBL_) {
        float r = fc_b[tid];
#pragma unroll
        for (int h = 0; h < H_; ++h) r = fmaf(zs[h], fc_w[tid * H_ + h], r);
        out[b * LBL_ + tid] = r;
    }
}

extern "C" void kernel_launch(void* const* d_in, const int* in_sizes, int n_in,
                              void* d_out, int out_size, void* d_ws, size_t ws_size,
                              hipStream_t stream)
{
    const float* x      = (const float*)d_in[0];
    const float* conv_w = (const float*)d_in[1];
    const float* conv_b = (const float*)d_in[2];
    const float* va_w1  = (const float*)d_in[3];
    const float* va_b1  = (const float*)d_in[4];
    const float* va_w2  = (const float*)d_in[5];
    const float* va_b2  = (const float*)d_in[6];
    const float* ta_w1  = (const float*)d_in[7];
    const float* ta_b1  = (const float*)d_in[8];
    const float* ta_w2  = (const float*)d_in[9];
    const float* ta_b2  = (const float*)d_in[10];
    const float* fc_w   = (const float*)d_in[11];
    const float* fc_b   = (const float*)d_in[12];

    float* ws    = (float*)d_ws;
    float* A     = ws;                          // 1728
    float* Abias = ws + 1728;                   // 64
    float* aw    = ws + 2048;                   // 32*8*84*64 = 1,376,256
    float* cwT2  = ws + 2048 + 1376256;         // 85*768    =    65,280
    float* v     = ws + 2048 + 1376256 + 65280; // 32*64*510 = 1,044,480

    precomp_kernel<<<1, 256, 0, stream>>>(conv_w, conv_b, va_w1, va_b1, A, Abias);
    transpose_kernel<<<128, 512, 0, stream>>>(conv_w, conv_b, cwT2);
    attn_kernel<<<dim3(8, B_), 1024, 0, stream>>>(x, va_w2, va_b2, A, Abias, aw);
    passB_kernel<<<dim3(8, B_, 8), 256, 0, stream>>>(x, cwT2, aw, v);
    ta_kernel<<<B_, 512, 0, stream>>>(v, ta_w1, ta_b1, ta_w2, ta_b2, fc_w, fc_b, (float*)d_out);
}

// Round 13
// 113.252 us; speedup vs baseline: 1.9469x; 1.9469x over previous
//
#include <hip/hip_runtime.h>
#include <hip/hip_bf16.h>

#define B_ 32
#define T_ 512
#define F_ 9
#define H_ 64
#define P_ 84
#define LE_ 510
#define LBL_ 10

struct CombT { int c[P_][3]; };
__host__ __device__ constexpr CombT make_combs() {
    CombT t{}; int n = 0;
    for (int a = 0; a < F_; ++a)
        for (int b = a + 1; b < F_; ++b)
            for (int c = b + 1; c < F_; ++c) { t.c[n][0] = a; t.c[n][1] = b; t.c[n][2] = c; ++n; }
    return t;
}
constexpr CombT COMB_H = make_combs();

// ---------------------------------------------------------------------------
// Kernel A: A[h][f*3+k] = sum_p va_w1[p] * sum_i [comb[p][i]==f] w[p,h,i,k]
//           Abias[h]    = va_b1[h] + sum_p va_w1[p]*conv_b[p,h]
// ---------------------------------------------------------------------------
__global__ __launch_bounds__(256) void precomp_kernel(
    const float* __restrict__ conv_w, const float* __restrict__ conv_b,
    const float* __restrict__ va_w1, const float* __restrict__ va_b1,
    float* __restrict__ A, float* __restrict__ Abias)
{
    __shared__ float sacc[256][28];
    int tid = threadIdx.x;
    int h = tid >> 2, q = tid & 3;            // 64 h  x  4 p-quarters
    for (int j = 0; j < 28; ++j) sacc[tid][j] = 0.f;
    for (int p = q * 21; p < (q + 1) * 21; ++p) {
        float w1 = va_w1[p];
        sacc[tid][27] += w1 * conv_b[p * H_ + h];
        const float* wp = conv_w + p * (H_ * 9) + h * 9;
        for (int i = 0; i < 3; ++i) {
            int f = COMB_H.c[p][i];
            for (int k = 0; k < 3; ++k) sacc[tid][f * 3 + k] += w1 * wp[i * 3 + k];
        }
    }
    __syncthreads();
    if (q == 0) {
        for (int j = 0; j < 27; ++j)
            A[h * 27 + j] = sacc[tid][j] + sacc[tid + 1][j] + sacc[tid + 2][j] + sacc[tid + 3][j];
        Abias[h] = va_b1[h] + sacc[tid][27] + sacc[tid + 1][27] + sacc[tid + 2][27] + sacc[tid + 3][27];
    }
}

// ---------------------------------------------------------------------------
// transpose_kernel: cwT2[p][h][12]: j=0..8 taps (i*3+k), j=9 bias, pad 2.
// ---------------------------------------------------------------------------
__global__ __launch_bounds__(512) void transpose_kernel(
    const float* __restrict__ conv_w, const float* __restrict__ conv_b,
    float* __restrict__ cwT2)
{
    int i = blockIdx.x * 512 + threadIdx.x;      // 85*768 = 65280
    if (i >= 85 * 768) return;
    int p = i / 768, r = i - p * 768;
    int h = r / 12, j = r - h * 12;
    float val = 0.f;
    if (p < P_) {
        if (j < 9) val = conv_w[(p * H_ + h) * 9 + j];
        else if (j == 9) val = conv_b[p * H_ + h];
    }
    cwT2[i] = val;
}

// ---------------------------------------------------------------------------
// attn_kernel: per (ltile, b), 1024 threads (16 waves), lane = l.
// ---------------------------------------------------------------------------
__global__ __launch_bounds__(1024) void attn_kernel(
    const float* __restrict__ x,
    const float* __restrict__ va_w2, const float* __restrict__ va_b2,
    const float* __restrict__ A, const float* __restrict__ Abias,
    float* __restrict__ aw)
{
    __shared__ float xs[66 * 9];
    __shared__ float t1s[64][65];
    __shared__ float t2s[64][85];

    const int b = blockIdx.y;
    const int lt = blockIdx.x;
    const int l0 = lt * 64;
    const int tid = threadIdx.x;
    const int ln = tid & 63;
    const int wv = tid >> 6;            // 0..15

    int maxidx = (T_ - l0) * F_; if (maxidx > 66 * F_) maxidx = 66 * F_;
    for (int i = tid; i < 66 * F_; i += 1024)
        xs[i] = (i < maxidx) ? x[b * (T_ * F_) + l0 * F_ + i] : 0.f;
    __syncthreads();

    float xw[27];
#pragma unroll
    for (int k = 0; k < 3; ++k)
#pragma unroll
        for (int f = 0; f < F_; ++f) xw[k * 9 + f] = xs[(ln + k) * F_ + f];

#pragma unroll
    for (int hh = 0; hh < 4; ++hh) {
        int h = wv * 4 + hh;
        const float* Ah = A + h * 27;
        float s = Abias[h];
#pragma unroll
        for (int f = 0; f < F_; ++f)
#pragma unroll
            for (int k = 0; k < 3; ++k) s = fmaf(xw[k * 9 + f], Ah[f * 3 + k], s);
        t1s[ln][h] = fmaxf(s, 0.f);
    }
    __syncthreads();

    const int cnt = (wv < 4) ? 6 : 5;
    const int p0 = (wv < 4) ? wv * 6 : 24 + (wv - 4) * 5;
    {
        float t2acc[6];
#pragma unroll
        for (int j = 0; j < 6; ++j) t2acc[j] = (j < cnt) ? va_b2[p0 + j] : 0.f;
        for (int h = 0; h < H_; ++h) {
            float tv = t1s[ln][h];
            const float* w2h = va_w2 + h * P_ + p0;
#pragma unroll
            for (int j = 0; j < 6; ++j)
                if (j < cnt) t2acc[j] = fmaf(tv, w2h[j], t2acc[j]);
        }
#pragma unroll
        for (int j = 0; j < 6; ++j)
            if (j < cnt) t2s[ln][p0 + j] = fmaxf(t2acc[j], 0.f);
    }
    __syncthreads();

    float mx = -1e30f;
    for (int p = 0; p < P_; ++p) mx = fmaxf(mx, t2s[ln][p]);
    float sum = 0.f;
    for (int p = 0; p < P_; ++p) sum += __expf(t2s[ln][p] - mx);
    float inv = 1.f / sum;

    const int awbase = (b * 8 + lt) * P_;
#pragma unroll
    for (int j = 0; j < 6; ++j)
        if (j < cnt)
            aw[(awbase + p0 + j) * 64 + ln] = __expf(t2s[ln][p0 + j] - mx) * inv;
}

// ---------------------------------------------------------------------------
// passB_kernel v11: grid (lt 8, b 32, z 4), 512 thr (8 waves), lane = l.
// Wave wv owns h-pair h0 = z*16 + wv*2; all 84 p's template-unrolled
// (static comb indices, xw[27] in VGPRs).  Weights: wave-uniform
// s_load_dwordx4 (SGPRs).  ap: aws LDS (R11 -- kills the R12 aw re-fetch).
// vs R11: 512-thr blocks + z=4 -> 4 blocks/CU = 32 waves/CU (8/SIMD),
// exactly one co-resident round (1024 blocks), hiding SMEM latency.
// ---------------------------------------------------------------------------
template<int PI>
__device__ __forceinline__ void pb_step(
    const float* __restrict__ wbase, const float* __restrict__ aws,
    const int ln, const float (&xw)[27], float& acc0, float& acc1)
{
    const int f0 = COMB_H.c[PI][0];     // folds: PI is a template constant
    const int f1 = COMB_H.c[PI][1];
    const int f2 = COMB_H.c[PI][2];
    const float4* wq = reinterpret_cast<const float4*>(wbase + PI * 768);
    const float4 w0 = wq[0], w1 = wq[1], w2 = wq[2];
    const float4 w3 = wq[3], w4 = wq[4], w5 = wq[5];
    const float ap = aws[PI * 64 + ln];

    float cv0 = w2.y;                    // bias h0
    cv0 = fmaf(w0.x, xw[0 * 9 + f0], cv0);
    cv0 = fmaf(w0.y, xw[1 * 9 + f0], cv0);
    cv0 = fmaf(w0.z, xw[2 * 9 + f0], cv0);
    cv0 = fmaf(w0.w, xw[0 * 9 + f1], cv0);
    cv0 = fmaf(w1.x, xw[1 * 9 + f1], cv0);
    cv0 = fmaf(w1.y, xw[2 * 9 + f1], cv0);
    cv0 = fmaf(w1.z, xw[0 * 9 + f2], cv0);
    cv0 = fmaf(w1.w, xw[1 * 9 + f2], cv0);
    cv0 = fmaf(w2.x, xw[2 * 9 + f2], cv0);

    float cv1 = w5.y;                    // bias h0+1
    cv1 = fmaf(w3.x, xw[0 * 9 + f0], cv1);
    cv1 = fmaf(w3.y, xw[1 * 9 + f0], cv1);
    cv1 = fmaf(w3.z, xw[2 * 9 + f0], cv1);
    cv1 = fmaf(w3.w, xw[0 * 9 + f1], cv1);
    cv1 = fmaf(w4.x, xw[1 * 9 + f1], cv1);
    cv1 = fmaf(w4.y, xw[2 * 9 + f1], cv1);
    cv1 = fmaf(w4.z, xw[0 * 9 + f2], cv1);
    cv1 = fmaf(w4.w, xw[1 * 9 + f2], cv1);
    cv1 = fmaf(w5.x, xw[2 * 9 + f2], cv1);

    acc0 = fmaf(ap, cv0, acc0);
    acc1 = fmaf(ap, cv1, acc1);
}

template<int PI, int N>
__device__ __forceinline__ void pb_run(
    const float* __restrict__ wbase, const float* __restrict__ aws,
    const int ln, const float (&xw)[27], float& acc0, float& acc1)
{
    if constexpr (N == 1) {
        pb_step<PI>(wbase, aws, ln, xw, acc0, acc1);
    } else {
        pb_run<PI, N / 2>(wbase, aws, ln, xw, acc0, acc1);
        pb_run<PI + N / 2, N - N / 2>(wbase, aws, ln, xw, acc0, acc1);
    }
}

__global__ __launch_bounds__(512, 8) void passB_kernel(
    const float* __restrict__ x,
    const float* __restrict__ cwT2,
    const float* __restrict__ aw,
    float* __restrict__ v)
{
    __shared__ float xraw[66 * 9];           //  2376 B
    __shared__ float aws[P_ * 64];           // 21504 B  [p][l]

    const int lt = blockIdx.x;
    const int b  = blockIdx.y;
    const int z  = blockIdx.z;               // 0..3
    const int l0 = lt * 64;
    const int tid = threadIdx.x;
    const int ln  = tid & 63;
    const int wvu = __builtin_amdgcn_readfirstlane(tid >> 6);   // 0..7 scalar

    // ---- stage x rows + aw slice (both coalesced) ----
    int maxidx = (T_ - l0) * F_; if (maxidx > 66 * F_) maxidx = 66 * F_;
    for (int i = tid; i < 66 * F_; i += 512)
        xraw[i] = (i < maxidx) ? x[b * (T_ * F_) + l0 * F_ + i] : 0.f;
    const float* awsrc = aw + (b * 8 + lt) * (P_ * 64);
    for (int i = tid; i < P_ * 64; i += 512)
        aws[i] = awsrc[i];
    __syncthreads();

    // ---- per-lane x window in registers (static indices only) ----
    float xw[27];
#pragma unroll
    for (int k = 0; k < 3; ++k)
#pragma unroll
        for (int f = 0; f < F_; ++f) xw[k * 9 + f] = xraw[(ln + k) * F_ + f];

    const int h0 = z * 16 + wvu * 2;
    const float* wbase = cwT2 + h0 * 12;     // + p*768
    float acc0 = 0.f, acc1 = 0.f;

    pb_run<0, P_>(wbase, aws, ln, xw, acc0, acc1);

    const int l = l0 + ln;
    if (l < LE_) {
        v[(b * H_ + h0 + 0) * LE_ + l] = acc0;
        v[(b * H_ + h0 + 1) * LE_ + l] = acc1;
    }
}

// ---------------------------------------------------------------------------
// ta_kernel v2 (proven R5): one block per b, 512 threads (8 waves).
// v layout [b][h][l]; all loads coalesced; shuffle reductions.
// ---------------------------------------------------------------------------
__global__ __launch_bounds__(512) void ta_kernel(
    const float* __restrict__ v,
    const float* __restrict__ ta_w1, const float* __restrict__ ta_b1,
    const float* __restrict__ ta_w2, const float* __restrict__ ta_b2,
    const float* __restrict__ fc_w, const float* __restrict__ fc_b,
    float* __restrict__ out)
{
    __shared__ float u1s[64];
    __shared__ float attns[512];
    __shared__ float red8[8];
    __shared__ float zs[64];

    const int b = blockIdx.x;
    const int tid = threadIdx.x;
    const int ln = tid & 63;
    const int wv = tid >> 6;             // 0..7
    const float* vb = v + b * (H_ * LE_);

#pragma unroll
    for (int hh = 0; hh < 8; ++hh) {
        const int h = wv * 8 + hh;
        const float* row = vb + h * LE_;
        float s = 0.f;
#pragma unroll
        for (int it = 0; it < 8; ++it) {
            int l = it * 64 + ln;
            if (l < LE_) s = fmaf(row[l], ta_w1[l], s);
        }
#pragma unroll
        for (int off = 32; off > 0; off >>= 1) s += __shfl_xor(s, off);
        if (ln == 0) u1s[h] = fmaxf(s + ta_b1[h], 0.f);
    }
    __syncthreads();

    float val = -1e30f;
    if (tid < LE_) {
        float s0 = ta_b2[tid], s1 = 0.f, s2 = 0.f, s3 = 0.f;
#pragma unroll
        for (int h = 0; h < H_; h += 4) {
            s0 = fmaf(u1s[h + 0], ta_w2[(h + 0) * LE_ + tid], s0);
            s1 = fmaf(u1s[h + 1], ta_w2[(h + 1) * LE_ + tid], s1);
            s2 = fmaf(u1s[h + 2], ta_w2[(h + 2) * LE_ + tid], s2);
            s3 = fmaf(u1s[h + 3], ta_w2[(h + 3) * LE_ + tid], s3);
        }
        val = fmaxf((s0 + s1) + (s2 + s3), 0.f);
    }

    float m = val;
#pragma unroll
    for (int off = 32; off > 0; off >>= 1) m = fmaxf(m, __shfl_xor(m, off));
    if (ln == 0) red8[wv] = m;
    __syncthreads();
    float M = red8[0];
#pragma unroll
    for (int i = 1; i < 8; ++i) M = fmaxf(M, red8[i]);

    float e = (tid < LE_) ? __expf(val - M) : 0.f;
    float s = e;
#pragma unroll
    for (int off = 32; off > 0; off >>= 1) s += __shfl_xor(s, off);
    __syncthreads();
    if (ln == 0) red8[wv] = s;
    __syncthreads();
    float S = red8[0];
#pragma unroll
    for (int i = 1; i < 8; ++i) S += red8[i];
    attns[tid] = e * (1.f / S);
    __syncthreads();

#pragma unroll
    for (int hh = 0; hh < 8; ++hh) {
        const int h = wv * 8 + hh;
        const float* row = vb + h * LE_;
        float t = 0.f;
#pragma unroll
        for (int it = 0; it < 8; ++it) {
            int l = it * 64 + ln;
            if (l < LE_) t = fmaf(row[l], attns[l], t);
        }
#pragma unroll
        for (int off = 32; off > 0; off >>= 1) t += __shfl_xor(t, off);
        if (ln == 0) zs[h] = t;
    }
    __syncthreads();

    if (tid < LBL_) {
        float r = fc_b[tid];
#pragma unroll
        for (int h = 0; h < H_; ++h) r = fmaf(zs[h], fc_w[tid * H_ + h], r);
        out[b * LBL_ + tid] = r;
    }
}

extern "C" void kernel_launch(void* const* d_in, const int* in_sizes, int n_in,
                              void* d_out, int out_size, void* d_ws, size_t ws_size,
                              hipStream_t stream)
{
    const float* x      = (const float*)d_in[0];
    const float* conv_w = (const float*)d_in[1];
    const float* conv_b = (const float*)d_in[2];
    const float* va_w1  = (const float*)d_in[3];
    const float* va_b1  = (const float*)d_in[4];
    const float* va_w2  = (const float*)d_in[5];
    const float* va_b2  = (const float*)d_in[6];
    const float* ta_w1  = (const float*)d_in[7];
    const float* ta_b1  = (const float*)d_in[8];
    const float* ta_w2  = (const float*)d_in[9];
    const float* ta_b2  = (const float*)d_in[10];
    const float* fc_w   = (const float*)d_in[11];
    const float* fc_b   = (const float*)d_in[12];

    float* ws    = (float*)d_ws;
    float* A     = ws;                          // 1728
    float* Abias = ws + 1728;                   // 64
    float* aw    = ws + 2048;                   // 32*8*84*64 = 1,376,256
    float* cwT2  = ws + 2048 + 1376256;         // 85*768    =    65,280
    float* v     = ws + 2048 + 1376256 + 65280; // 32*64*510 = 1,044,480

    precomp_kernel<<<1, 256, 0, stream>>>(conv_w, conv_b, va_w1, va_b1, A, Abias);
    transpose_kernel<<<128, 512, 0, stream>>>(conv_w, conv_b, cwT2);
    attn_kernel<<<dim3(8, B_), 1024, 0, stream>>>(x, va_w2, va_b2, A, Abias, aw);
    passB_kernel<<<dim3(8, B_, 4), 512, 0, stream>>>(x, cwT2, aw, v);
    ta_kernel<<<B_, 512, 0, stream>>>(v, ta_w1, ta_b1, ta_w2, ta_b2, fc_w, fc_b, (float*)d_out);
}